// Round 7
// baseline (110.138 us; speedup 1.0000x reference)
//
#include <hip/hip_runtime.h>
#include <hip/hip_fp16.h>
#include <math.h>

// Problem constants (fixed by reference)
#define NI_TOT 100000
#define NJ_TOT 100000
#define DD 8
#define SI_N 6000
#define SJ_N 6000
#define NNZ_N 500000
#define EPSF 1e-6f
#define LOG2E 1.44269504088896f
#define INV_LOG2E 0.693147180559945f
#define L2SQ (LOG2E * LOG2E)

// Dense geometry: block = 32 i-rows (LDS) x 1024 j-cols (4/thread in regs).
// R2 lesson: grid must stay >= ~2048 blocks (latency-bound, needs residency).
// R4 lesson: i-rows via LDS broadcast, NOT scalar s_load chains (2x slower).
// R4/R5 lesson: no ticket/__threadfence epilogue (~40-50us L2 writeback cost).
// R6 lesson: halving LDS bytes/VALU did NOT move total -> hot loop is
// LATENCY-exposed, not issue-bound. This round: TI 64->32, JPT 2->4 at
// CONSTANT grid (1128 dense blocks) -> 4 independent sqrt/exp chains per
// thread (2x ILP) and half the ds_read cost per pair. R2 conflated JPT=4
// with a halved grid; this isolates the ILP variable.
#define TI 32
#define JPT 4
#define JTILE (256 * JPT)                     // 1024
#define ND_I ((SI_N + TI - 1) / TI)           // 188
#define NJT ((SJ_N + JTILE - 1) / JTILE)      // 6
#define N_DENSE_BLOCKS (ND_I * NJT)           // 1128
// Sparse: 2 links per thread
#define LPT 2
#define SPARSE_SPAN (256 * LPT)               // 512
#define N_SPARSE_BLOCKS ((NNZ_N + SPARSE_SPAN - 1) / SPARSE_SPAN) // 977
#define N_TOTAL_BLOCKS (N_DENSE_BLOCKS + N_SPARSE_BLOCKS)         // 2105

// Workspace layout: [fp16 z rows: 200K x 16B][fp16 biases: 200K x 2B][partials]
// fp16 cache keeps sparse gather footprint 3.6MB (L2-resident per XCD);
// R1 measured: dropping it cost 44MB HBM FETCH.
#define NROWS (NI_TOT + NJ_TOT)
#define HZ_BYTES ((size_t)NROWS * DD * 2)     // 3.2 MB
#define HB_BYTES ((size_t)NROWS * 2)          // 400 KB
#define PARTIALS_OFF (HZ_BYTES + HB_BYTES)    // 3.6 MB (16B aligned)

// A&S 6.1.36: Gamma(1+x) = 1 + a1 x + ... + a8 x^8, 0<=x<=1, |eps|<=3e-7
#define GA1 (-0.577191652f)
#define GA2 ( 0.988205891f)
#define GA3 (-0.897056937f)
#define GA4 ( 0.918206857f)
#define GA5 (-0.756704078f)
#define GA6 ( 0.482199394f)
#define GA7 (-0.193527818f)
#define GA8 ( 0.035868343f)

typedef _Float16 h2 __attribute__((ext_vector_type(2)));

#if defined(__has_builtin)
#if __has_builtin(__builtin_amdgcn_fdot2)
#define HAVE_FDOT2 1
#endif
#endif

__device__ __forceinline__ h2 u2h(unsigned u) {
    union { unsigned v; h2 h; } c; c.v = u; return c.h;
}
__device__ __forceinline__ unsigned pack2h(float x, float y) {
    union { unsigned v; h2 h; } c;
    c.h[0] = (_Float16)x; c.h[1] = (_Float16)y;
    return c.v;
}
__device__ __forceinline__ float fdot2f(h2 a, h2 b, float c) {
#ifdef HAVE_FDOT2
    return __builtin_amdgcn_fdot2(a, b, c, false);
#else
    return fmaf((float)a[0], (float)b[0], fmaf((float)a[1], (float)b[1], c));
#endif
}

// ---- prep: pack z rows (16B/row) and biases to fp16 in workspace ----
__global__ __launch_bounds__(256) void pack_kernel(
    const float* __restrict__ beta, const float* __restrict__ gamma,
    const float* __restrict__ zi_all, const float* __restrict__ zj_all,
    __half* __restrict__ hz, __half* __restrict__ hb)
{
    const int r = blockIdx.x * 256 + threadIdx.x;
    if (r < NROWS) {
        const float* src = (r < NI_TOT) ? zi_all + (size_t)r * DD
                                        : zj_all + (size_t)(r - NI_TOT) * DD;
        float4 a = ((const float4*)src)[0];
        float4 b = ((const float4*)src)[1];
        __half2 h0 = __floats2half2_rn(a.x, a.y);
        __half2 h1 = __floats2half2_rn(a.z, a.w);
        __half2 h2v = __floats2half2_rn(b.x, b.y);
        __half2 h3 = __floats2half2_rn(b.z, b.w);
        uint4 u;
        u.x = *(unsigned*)&h0; u.y = *(unsigned*)&h1;
        u.z = *(unsigned*)&h2v; u.w = *(unsigned*)&h3;
        ((uint4*)hz)[r] = u;
    } else if (r < 2 * NROWS) {
        const int q = r - NROWS;
        float v = (q < NI_TOT) ? beta[q] : gamma[q - NI_TOT];
        hb[q] = __float2half(v);
    }
}

__device__ __forceinline__ void unpack_row(uint4 u, float f[DD]) {
    float2 p;
    p = __half22float2(*(__half2*)&u.x); f[0] = p.x; f[1] = p.y;
    p = __half22float2(*(__half2*)&u.y); f[2] = p.x; f[3] = p.y;
    p = __half22float2(*(__half2*)&u.z); f[4] = p.x; f[5] = p.y;
    p = __half22float2(*(__half2*)&u.w); f[6] = p.x; f[7] = p.y;
}

template<int MODE>   // 0 = workspace path, 1 = f32 fallback (atomic out)
__global__ __launch_bounds__(256) void fused_kernel(
    const float* __restrict__ beta, const float* __restrict__ gamma,
    const float* __restrict__ zi_all, const float* __restrict__ zj_all,
    const float* __restrict__ valueC,
    const int* __restrict__ si, const int* __restrict__ sj,       // dense samples
    const int* __restrict__ spi, const int* __restrict__ spj,     // sparse links
    const __half* __restrict__ hz, const __half* __restrict__ hb, // fp16 packed
    float* __restrict__ partials, float* __restrict__ out)
{
    __shared__ float sRed[4];
    // Dense i-tile: per row 32B = {4x half2 m_d, f32 seedL, f32 e^beta, pad2}
    // m_d = -2*L^2*(zi_d+EPS) in fp16; seedL = L^2*|zi+EPS|^2 (f32, pre-round).
    __shared__ __align__(16) unsigned sRow[TI * 8];

    const int t = threadIdx.x;
    float blocksum = 0.0f;  // signed contribution of this block to LL

    if (blockIdx.x < N_DENSE_BLOCKS) {
        // -------- dense non-link: -sum(exp(beta_i + gamma_j - |zi-zj|)) --------
        // e^{b+g-d} = (e^b)_row * (e^g)_col * exp2(-L*d).
        // (L*d)^2 = L^2|a|^2 + L^2|b|^2 + sum(m_d * b_d), a = zi+EPS, b = zj,
        // m = -2 L^2 a  -> 4 chained fdot2 seeded with L^2|a|^2.
        const int it = blockIdx.x % ND_I;
        const int js = blockIdx.x / ND_I;
        const int i0 = it * TI;

        // Stage i-tile rows: 32 threads, 16B gathers (other threads gather j).
        if (t < TI) {
            const int gi = i0 + t;
            uint4 mh = make_uint4(0u, 0u, 0u, 0u);
            float seedL = 0.f, eb = 0.f;     // pad row -> zero contribution
            if (gi < SI_N) {
                const int row = si[gi];
                float a[DD];
                if (MODE == 0) {
                    uint4 raw = ((const uint4*)hz)[row];
                    float f[DD]; unpack_row(raw, f);
#pragma unroll
                    for (int d = 0; d < DD; ++d) a[d] = f[d] + EPSF;
                } else {
                    const float4* zp = (const float4*)(zi_all + (size_t)row * DD);
                    float4 p0 = zp[0], p1 = zp[1];
                    a[0]=p0.x+EPSF; a[1]=p0.y+EPSF; a[2]=p0.z+EPSF; a[3]=p0.w+EPSF;
                    a[4]=p1.x+EPSF; a[5]=p1.y+EPSF; a[6]=p1.z+EPSF; a[7]=p1.w+EPSF;
                }
                float s = 0.f;
#pragma unroll
                for (int d = 0; d < DD; ++d) s = fmaf(a[d], a[d], s);
                seedL = s * L2SQ;
                eb = __builtin_amdgcn_exp2f(beta[row] * LOG2E);
                const float k = -2.0f * L2SQ;
                mh.x = pack2h(a[0]*k, a[1]*k);
                mh.y = pack2h(a[2]*k, a[3]*k);
                mh.z = pack2h(a[4]*k, a[5]*k);
                mh.w = pack2h(a[6]*k, a[7]*k);
            }
            *(uint4*)&sRow[t * 8] = mh;
            sRow[t * 8 + 4] = __float_as_uint(seedL);
            sRow[t * 8 + 5] = __float_as_uint(eb);
        }

        // Gather this thread's 4 j-columns (fp16) into registers.
        const int jb = js * JTILE + t * JPT;
        uint4 ch[JPT]; float s2[JPT], gf[JPT];
#pragma unroll
        for (int u = 0; u < JPT; ++u) {
            int gj = jb + u;
            if (gj < SJ_N) {
                int row = sj[gj];
                if (MODE == 0) {
                    ch[u] = ((const uint4*)hz)[NI_TOT + row];
                } else {
                    const float4* q = (const float4*)(zj_all + (size_t)row * DD);
                    float4 q0 = q[0], q1 = q[1];
                    ch[u].x = pack2h(q0.x, q0.y); ch[u].y = pack2h(q0.z, q0.w);
                    ch[u].z = pack2h(q1.x, q1.y); ch[u].w = pack2h(q1.z, q1.w);
                }
                float s = fdot2f(u2h(ch[u].x), u2h(ch[u].x),
                          fdot2f(u2h(ch[u].y), u2h(ch[u].y),
                          fdot2f(u2h(ch[u].z), u2h(ch[u].z),
                          fdot2f(u2h(ch[u].w), u2h(ch[u].w), 0.0f))));
                s2[u] = s * L2SQ;                          // L^2 |b|^2
                gf[u] = __builtin_amdgcn_exp2f(gamma[row] * LOG2E);
            } else {
                ch[u] = make_uint4(0u, 0u, 0u, 0u);
                s2[u] = 0.0f;
                gf[u] = 0.0f;  // pad col -> zero contribution
            }
        }
        __syncthreads();  // i-tile ready

        // ---- hot loop: 32 i-rows x 4 cols, barrier-free, row rotated 1 ahead.
        // 4 independent sqrt/exp chains per thread; 18 LDS-cyc amortized /4 cols.
        float acc[JPT] = {0.0f, 0.0f, 0.0f, 0.0f};
        uint4  cr  = *(const uint4*)&sRow[0];
        float2 cib = *(const float2*)&sRow[4];
#pragma unroll 4
        for (int a = 0; a < TI; ++a) {
            uint4 nr; float2 nib;
            if (a + 1 < TI) {              // prefetch next row (broadcast ds_read)
                nr  = *(const uint4*)&sRow[(a + 1) * 8];
                nib = *(const float2*)&sRow[(a + 1) * 8 + 4];
            }
#pragma unroll
            for (int u = 0; u < JPT; ++u) {
                float dd;
                dd = fdot2f(u2h(cr.x), u2h(ch[u].x), cib.x);  // seed L^2|a|^2
                dd = fdot2f(u2h(cr.y), u2h(ch[u].y), dd);
                dd = fdot2f(u2h(cr.z), u2h(ch[u].z), dd);
                dd = fdot2f(u2h(cr.w), u2h(ch[u].w), dd);
                float ss = fmaxf(dd + s2[u], 1e-20f);  // (L*dist)^2
                float dist = __builtin_amdgcn_sqrtf(ss);
                float e = __builtin_amdgcn_exp2f(-dist);   // neg = free src modifier
                acc[u] = fmaf(cib.y, e, acc[u]);           // * e^beta_row
            }
            cr = nr; cib = nib;
        }
        float bs = 0.0f;
#pragma unroll
        for (int u = 0; u < JPT; ++u) bs = fmaf(gf[u], acc[u], bs);  // * e^gamma_col
        blocksum = -bs;   // dense term enters LL negatively
    } else {
        // ---------------- sparse link term: Poisson log-likelihood ----------------
        const int base = (blockIdx.x - N_DENSE_BLOCKS) * SPARSE_SPAN + t;
        float val = 0.0f;
        const uint4* hzv = (const uint4*)hz;
#pragma unroll
        for (int u = 0; u < LPT; ++u) {
            const int idx = base + u * 256;
            if (idx >= NNZ_N) continue;
            const int i = spi[idx], j = spj[idx];
            const float c = valueC[idx];
            float dist, bg;
            if (MODE == 0) {
                // fp16 packed path: 16B/row gathers, fp16 biases (L2-resident)
                uint4 ui = hzv[i];
                uint4 uj = hzv[NI_TOT + j];
                float fi[DD], fj[DD];
                unpack_row(ui, fi);
                unpack_row(uj, fj);
                float ss = 0.0f;
#pragma unroll
                for (int d = 0; d < DD; ++d) {
                    float df = fi[d] - fj[d] + EPSF;
                    ss = fmaf(df, df, ss);
                }
                ss = fmaxf(ss, 1e-20f);
                dist = __builtin_amdgcn_sqrtf(ss);
                bg = __half2float(hb[i]) + __half2float(hb[NI_TOT + j]);
            } else {
                // f32 fallback (no workspace)
                const float4* zi4 = (const float4*)(zi_all + (size_t)i * DD);
                const float4* zj4 = (const float4*)(zj_all + (size_t)j * DD);
                float4 a0 = zi4[0], a1 = zi4[1];
                float4 b0 = zj4[0], b1 = zj4[1];
                float ss = 0.0f, df;
                df = a0.x-b0.x+EPSF; ss = fmaf(df,df,ss);
                df = a0.y-b0.y+EPSF; ss = fmaf(df,df,ss);
                df = a0.z-b0.z+EPSF; ss = fmaf(df,df,ss);
                df = a0.w-b0.w+EPSF; ss = fmaf(df,df,ss);
                df = a1.x-b1.x+EPSF; ss = fmaf(df,df,ss);
                df = a1.y-b1.y+EPSF; ss = fmaf(df,df,ss);
                df = a1.z-b1.z+EPSF; ss = fmaf(df,df,ss);
                df = a1.w-b1.w+EPSF; ss = fmaf(df,df,ss);
                ss = fmaxf(ss, 1e-20f);
                dist = __builtin_amdgcn_sqrtf(ss);
                bg = beta[i] + gamma[j];
            }
            // gammaln(c+1) via A&S 6.1.36 poly (|e|<=3e-7), ln = log2/log2e
            float g = 1.0f + c*(GA1 + c*(GA2 + c*(GA3 + c*(GA4 + c*(GA5
                          + c*(GA6 + c*(GA7 + c*GA8)))))));
            val += c * (bg - dist) - __builtin_amdgcn_logf(g) * INV_LOG2E;
        }
        blocksum = val;  // positive sign
    }

    // Block reduction: wave shuffle then cross-wave via LDS
    float acc = blocksum;
#pragma unroll
    for (int off = 32; off; off >>= 1) acc += __shfl_down(acc, off, 64);
    const int lane = t & 63, w = t >> 6;
    if (lane == 0) sRed[w] = acc;
    __syncthreads();
    if (t == 0) {
        float s = sRed[0] + sRed[1] + sRed[2] + sRed[3];
        if (MODE) atomicAdd(out, s);
        else partials[blockIdx.x] = s;
    }
}

__global__ __launch_bounds__(256) void final_reduce_kernel(
    const float* __restrict__ p, int n, float* __restrict__ out)
{
    __shared__ float sRed[4];
    float s0 = 0.0f, s1 = 0.0f, s2 = 0.0f, s3 = 0.0f;
    int i = threadIdx.x;
    for (; i + 768 < n; i += 1024) {      // 4 independent chains to pipeline loads
        s0 += p[i]; s1 += p[i + 256]; s2 += p[i + 512]; s3 += p[i + 768];
    }
    for (; i < n; i += 256) s0 += p[i];
    float s = (s0 + s1) + (s2 + s3);
#pragma unroll
    for (int off = 32; off; off >>= 1) s += __shfl_down(s, off, 64);
    const int lane = threadIdx.x & 63, w = threadIdx.x >> 6;
    if (lane == 0) sRed[w] = s;
    __syncthreads();
    if (threadIdx.x == 0) out[0] = sRed[0] + sRed[1] + sRed[2] + sRed[3];
}

extern "C" void kernel_launch(void* const* d_in, const int* in_sizes, int n_in,
                              void* d_out, int out_size, void* d_ws, size_t ws_size,
                              hipStream_t stream) {
    const float* beta   = (const float*)d_in[0];
    const float* gamma  = (const float*)d_in[1];
    const float* zi     = (const float*)d_in[2];
    const float* zj     = (const float*)d_in[3];
    const float* valueC = (const float*)d_in[4];
    const int* si   = (const int*)d_in[5];
    const int* sjx  = (const int*)d_in[6];
    const int* spi  = (const int*)d_in[7];
    const int* spj  = (const int*)d_in[8];
    float* out = (float*)d_out;

    const int ntot = N_TOTAL_BLOCKS;
    const size_t need = PARTIALS_OFF + (size_t)ntot * sizeof(float);

    if (d_ws && ws_size >= need) {
        __half* hz = (__half*)d_ws;
        __half* hb = (__half*)((char*)d_ws + HZ_BYTES);
        float* p = (float*)((char*)d_ws + PARTIALS_OFF);
        const int packb = (2 * NROWS + 255) / 256;      // 1563
        pack_kernel<<<packb, 256, 0, stream>>>(beta, gamma, zi, zj, hz, hb);
        fused_kernel<0><<<ntot, 256, 0, stream>>>(
            beta, gamma, zi, zj, valueC, si, sjx, spi, spj, hz, hb, p, out);
        final_reduce_kernel<<<1, 256, 0, stream>>>(p, ntot, out);
    } else {
        // Fallback: f32 sparse + atomic accumulation directly into d_out
        hipMemsetAsync(out, 0, sizeof(float), stream);
        fused_kernel<1><<<ntot, 256, 0, stream>>>(
            beta, gamma, zi, zj, valueC, si, sjx, spi, spj,
            (const __half*)zi, (const __half*)zi, nullptr, out);
    }
}

// Round 8
// 98.186 us; speedup vs baseline: 1.1217x; 1.1217x over previous
//
#include <hip/hip_runtime.h>
#include <hip/hip_fp16.h>
#include <math.h>

// Problem constants (fixed by reference)
#define NI_TOT 100000
#define NJ_TOT 100000
#define DD 8
#define SI_N 6000
#define SJ_N 6000
#define NNZ_N 500000
#define EPSF 1e-6f
#define LOG2E 1.44269504088896f
#define INV_LOG2E 0.693147180559945f
#define L2SQ (LOG2E * LOG2E)

// Dense geometry: block = 64 i-rows (LDS) x 512 j-cols (2/thread in regs).
// R2 lesson: grid must stay >= ~2048 blocks (latency-bound, needs residency).
// R4 lesson: i-rows via LDS broadcast, NOT scalar s_load chains (2x slower).
// R4/R5 lesson: no ticket/__threadfence epilogue (~40-50us L2 writeback cost).
// R6/R7 lesson: hot-loop LDS/VALU/ILP changes are all NULL -> the cost was
// never the loop. Audit: each j-column was re-gathered ND_I=94x through sj[]
// (~1.15M random gathers across dense prologues == size of whole sparse
// phase). This round: jrec/irec tables computed ONCE in pack, read COALESCED
// by dense blocks. Hot loop/sparse/3-dispatch structure identical to R6.
#define TI 64
#define JPT 2
#define JTILE (256 * JPT)                     // 512
#define ND_I ((SI_N + TI - 1) / TI)           // 94
#define NJT ((SJ_N + JTILE - 1) / JTILE)      // 12
#define N_DENSE_BLOCKS (ND_I * NJT)           // 1128
// Sparse: 2 links per thread
#define LPT 2
#define SPARSE_SPAN (256 * LPT)               // 512
#define N_SPARSE_BLOCKS ((NNZ_N + SPARSE_SPAN - 1) / SPARSE_SPAN) // 977
#define N_TOTAL_BLOCKS (N_DENSE_BLOCKS + N_SPARSE_BLOCKS)         // 2105

// Workspace layout:
//  [fp16 z rows 200K x 16B][fp16 biases 200K x 2B]
//  [irec 6016 x 32B][jrec 6144 x 32B][partials]
// fp16 cache keeps sparse gather footprint 3.6MB (L2-resident per XCD);
// R1 measured: dropping it cost 44MB HBM FETCH.
// irec[gi] = {4x half2 m_d = -2*L^2*(zi+EPS), f32 seedL = L^2|zi+EPS|^2,
//             f32 e^beta, pad2}  (pad rows all-zero -> zero contribution)
// jrec[gj] = {4x half2 zj, f32 s2 = L^2|zj|^2, f32 e^gamma, pad2}
#define NROWS (NI_TOT + NJ_TOT)
#define HZ_BYTES ((size_t)NROWS * DD * 2)     // 3,200,000
#define HB_BYTES ((size_t)NROWS * 2)          // 400,000
#define IREC_N (ND_I * TI)                    // 6016
#define JREC_N (NJT * JTILE)                  // 6144
#define IREC_OFF (HZ_BYTES + HB_BYTES)        // 3,600,000
#define IREC_BYTES ((size_t)IREC_N * 32)      // 192,512
#define JREC_OFF (IREC_OFF + IREC_BYTES)      // 3,792,512
#define JREC_BYTES ((size_t)JREC_N * 32)      // 196,608
#define PART_OFF (JREC_OFF + JREC_BYTES)      // 3,989,120
#define WS_NEED (PART_OFF + (size_t)N_TOTAL_BLOCKS * 4)

// A&S 6.1.36: Gamma(1+x) = 1 + a1 x + ... + a8 x^8, 0<=x<=1, |eps|<=3e-7
#define GA1 (-0.577191652f)
#define GA2 ( 0.988205891f)
#define GA3 (-0.897056937f)
#define GA4 ( 0.918206857f)
#define GA5 (-0.756704078f)
#define GA6 ( 0.482199394f)
#define GA7 (-0.193527818f)
#define GA8 ( 0.035868343f)

typedef _Float16 h2 __attribute__((ext_vector_type(2)));

#if defined(__has_builtin)
#if __has_builtin(__builtin_amdgcn_fdot2)
#define HAVE_FDOT2 1
#endif
#endif

__device__ __forceinline__ h2 u2h(unsigned u) {
    union { unsigned v; h2 h; } c; c.v = u; return c.h;
}
__device__ __forceinline__ unsigned pack2h(float x, float y) {
    union { unsigned v; h2 h; } c;
    c.h[0] = (_Float16)x; c.h[1] = (_Float16)y;
    return c.v;
}
__device__ __forceinline__ float fdot2f(h2 a, h2 b, float c) {
#ifdef HAVE_FDOT2
    return __builtin_amdgcn_fdot2(a, b, c, false);
#else
    return fmaf((float)a[0], (float)b[0], fmaf((float)a[1], (float)b[1], c));
#endif
}

// ---- prep: fp16 tables + sequential dense i/j records ----
__global__ __launch_bounds__(256) void pack_kernel(
    const float* __restrict__ beta, const float* __restrict__ gamma,
    const float* __restrict__ zi_all, const float* __restrict__ zj_all,
    const int* __restrict__ si, const int* __restrict__ sj,
    __half* __restrict__ hz, __half* __restrict__ hb,
    unsigned* __restrict__ irec, unsigned* __restrict__ jrec)
{
    const int r = blockIdx.x * 256 + threadIdx.x;
    if (r < NROWS) {
        const float* src = (r < NI_TOT) ? zi_all + (size_t)r * DD
                                        : zj_all + (size_t)(r - NI_TOT) * DD;
        float4 a = ((const float4*)src)[0];
        float4 b = ((const float4*)src)[1];
        uint4 u;
        u.x = pack2h(a.x, a.y); u.y = pack2h(a.z, a.w);
        u.z = pack2h(b.x, b.y); u.w = pack2h(b.z, b.w);
        ((uint4*)hz)[r] = u;
    } else if (r < 2 * NROWS) {
        const int q = r - NROWS;
        float v = (q < NI_TOT) ? beta[q] : gamma[q - NI_TOT];
        hb[q] = __float2half(v);
    } else if (r < 2 * NROWS + IREC_N) {
        const int q = r - 2 * NROWS;
        uint4 mh = make_uint4(0u, 0u, 0u, 0u);
        float seedL = 0.f, eb = 0.f;          // pad row -> zero contribution
        if (q < SI_N) {
            const int row = si[q];
            const float4* zp = (const float4*)(zi_all + (size_t)row * DD);
            float4 p0 = zp[0], p1 = zp[1];
            float a[DD];
            a[0]=p0.x+EPSF; a[1]=p0.y+EPSF; a[2]=p0.z+EPSF; a[3]=p0.w+EPSF;
            a[4]=p1.x+EPSF; a[5]=p1.y+EPSF; a[6]=p1.z+EPSF; a[7]=p1.w+EPSF;
            float s = 0.f;
#pragma unroll
            for (int d = 0; d < DD; ++d) s = fmaf(a[d], a[d], s);
            seedL = s * L2SQ;
            eb = __builtin_amdgcn_exp2f(beta[row] * LOG2E);
            const float k = -2.0f * L2SQ;
            mh.x = pack2h(a[0]*k, a[1]*k);
            mh.y = pack2h(a[2]*k, a[3]*k);
            mh.z = pack2h(a[4]*k, a[5]*k);
            mh.w = pack2h(a[6]*k, a[7]*k);
        }
        unsigned* op = irec + (size_t)q * 8;
        *(uint4*)op = mh;
        op[4] = __float_as_uint(seedL);
        op[5] = __float_as_uint(eb);
        op[6] = 0u; op[7] = 0u;
    } else if (r < 2 * NROWS + IREC_N + JREC_N) {
        const int q = r - 2 * NROWS - IREC_N;
        uint4 ch = make_uint4(0u, 0u, 0u, 0u);
        float s2 = 0.f, gf = 0.f;             // pad col -> zero contribution
        if (q < SJ_N) {
            const int row = sj[q];
            const float4* zp = (const float4*)(zj_all + (size_t)row * DD);
            float4 q0 = zp[0], q1 = zp[1];
            ch.x = pack2h(q0.x, q0.y); ch.y = pack2h(q0.z, q0.w);
            ch.z = pack2h(q1.x, q1.y); ch.w = pack2h(q1.z, q1.w);
            float s = fdot2f(u2h(ch.x), u2h(ch.x),
                      fdot2f(u2h(ch.y), u2h(ch.y),
                      fdot2f(u2h(ch.z), u2h(ch.z),
                      fdot2f(u2h(ch.w), u2h(ch.w), 0.0f))));
            s2 = s * L2SQ;
            gf = __builtin_amdgcn_exp2f(gamma[row] * LOG2E);
        }
        unsigned* op = jrec + (size_t)q * 8;
        *(uint4*)op = ch;
        op[4] = __float_as_uint(s2);
        op[5] = __float_as_uint(gf);
        op[6] = 0u; op[7] = 0u;
    }
}

__device__ __forceinline__ void unpack_row(uint4 u, float f[DD]) {
    float2 p;
    p = __half22float2(*(__half2*)&u.x); f[0] = p.x; f[1] = p.y;
    p = __half22float2(*(__half2*)&u.y); f[2] = p.x; f[3] = p.y;
    p = __half22float2(*(__half2*)&u.z); f[4] = p.x; f[5] = p.y;
    p = __half22float2(*(__half2*)&u.w); f[6] = p.x; f[7] = p.y;
}

template<int MODE>   // 0 = workspace path, 1 = f32 fallback (atomic out)
__global__ __launch_bounds__(256) void fused_kernel(
    const float* __restrict__ beta, const float* __restrict__ gamma,
    const float* __restrict__ zi_all, const float* __restrict__ zj_all,
    const float* __restrict__ valueC,
    const int* __restrict__ si, const int* __restrict__ sj,       // dense samples
    const int* __restrict__ spi, const int* __restrict__ spj,     // sparse links
    const __half* __restrict__ hz, const __half* __restrict__ hb, // fp16 packed
    const unsigned* __restrict__ irec, const unsigned* __restrict__ jrec,
    float* __restrict__ partials, float* __restrict__ out)
{
    __shared__ float sRed[4];
    // Dense i-tile: per row 32B = {4x half2 m_d, f32 seedL, f32 e^beta, pad2}
    __shared__ __align__(16) unsigned sRow[TI * 8];

    const int t = threadIdx.x;
    float blocksum = 0.0f;  // signed contribution of this block to LL

    if (blockIdx.x < N_DENSE_BLOCKS) {
        // -------- dense non-link: -sum(exp(beta_i + gamma_j - |zi-zj|)) --------
        // e^{b+g-d} = (e^b)_row * (e^g)_col * exp2(-L*d).
        // (L*d)^2 = L^2|a|^2 + L^2|b|^2 + sum(m_d * b_d), a = zi+EPS, b = zj.
        const int it = blockIdx.x % ND_I;
        const int js = blockIdx.x / ND_I;
        const int i0 = it * TI;

        if (MODE == 0) {
            // Stage i-tile: 128 COALESCED uint4 from irec (2KB, computed once).
            if (t < (TI * 8) / 4)
                ((uint4*)sRow)[t] = ((const uint4*)(irec + (size_t)i0 * 8))[t];
        } else {
            // Fallback: build records in-kernel (gathered, as R6)
            if (t < TI) {
                const int gi = i0 + t;
                uint4 mh = make_uint4(0u, 0u, 0u, 0u);
                float seedL = 0.f, eb = 0.f;
                if (gi < SI_N) {
                    const int row = si[gi];
                    const float4* zp = (const float4*)(zi_all + (size_t)row * DD);
                    float4 p0 = zp[0], p1 = zp[1];
                    float a[DD];
                    a[0]=p0.x+EPSF; a[1]=p0.y+EPSF; a[2]=p0.z+EPSF; a[3]=p0.w+EPSF;
                    a[4]=p1.x+EPSF; a[5]=p1.y+EPSF; a[6]=p1.z+EPSF; a[7]=p1.w+EPSF;
                    float s = 0.f;
#pragma unroll
                    for (int d = 0; d < DD; ++d) s = fmaf(a[d], a[d], s);
                    seedL = s * L2SQ;
                    eb = __builtin_amdgcn_exp2f(beta[row] * LOG2E);
                    const float k = -2.0f * L2SQ;
                    mh.x = pack2h(a[0]*k, a[1]*k);
                    mh.y = pack2h(a[2]*k, a[3]*k);
                    mh.z = pack2h(a[4]*k, a[5]*k);
                    mh.w = pack2h(a[6]*k, a[7]*k);
                }
                *(uint4*)&sRow[t * 8] = mh;
                sRow[t * 8 + 4] = __float_as_uint(seedL);
                sRow[t * 8 + 5] = __float_as_uint(eb);
            }
        }

        // This thread's 2 j-columns: COALESCED reads from jrec (no sj
        // indirection, no bounds branch -- jrec padded to NJT*JTILE).
        const int jb = js * JTILE + t * JPT;
        uint4 ch[JPT]; float s2[JPT], gf[JPT];
#pragma unroll
        for (int u = 0; u < JPT; ++u) {
            if (MODE == 0) {
                const unsigned* jr = jrec + (size_t)(jb + u) * 8;
                ch[u] = *(const uint4*)jr;
                float2 sg = *(const float2*)(jr + 4);
                s2[u] = sg.x;
                gf[u] = sg.y;
            } else {
                int gj = jb + u;
                if (gj < SJ_N) {
                    int row = sj[gj];
                    const float4* q = (const float4*)(zj_all + (size_t)row * DD);
                    float4 q0 = q[0], q1 = q[1];
                    ch[u].x = pack2h(q0.x, q0.y); ch[u].y = pack2h(q0.z, q0.w);
                    ch[u].z = pack2h(q1.x, q1.y); ch[u].w = pack2h(q1.z, q1.w);
                    float s = fdot2f(u2h(ch[u].x), u2h(ch[u].x),
                              fdot2f(u2h(ch[u].y), u2h(ch[u].y),
                              fdot2f(u2h(ch[u].z), u2h(ch[u].z),
                              fdot2f(u2h(ch[u].w), u2h(ch[u].w), 0.0f))));
                    s2[u] = s * L2SQ;
                    gf[u] = __builtin_amdgcn_exp2f(gamma[row] * LOG2E);
                } else {
                    ch[u] = make_uint4(0u, 0u, 0u, 0u);
                    s2[u] = 0.0f;
                    gf[u] = 0.0f;
                }
            }
        }
        __syncthreads();  // i-tile ready

        // ---- hot loop: 64 i-rows, barrier-free, row rotated 1 ahead ----
        float acc[JPT] = {0.0f, 0.0f};
        uint4  cr  = *(const uint4*)&sRow[0];
        float2 cib = *(const float2*)&sRow[4];
#pragma unroll 4
        for (int a = 0; a < TI; ++a) {
            uint4 nr; float2 nib;
            if (a + 1 < TI) {              // prefetch next row (broadcast ds_read)
                nr  = *(const uint4*)&sRow[(a + 1) * 8];
                nib = *(const float2*)&sRow[(a + 1) * 8 + 4];
            }
#pragma unroll
            for (int u = 0; u < JPT; ++u) {
                float dd;
                dd = fdot2f(u2h(cr.x), u2h(ch[u].x), cib.x);  // seed L^2|a|^2
                dd = fdot2f(u2h(cr.y), u2h(ch[u].y), dd);
                dd = fdot2f(u2h(cr.z), u2h(ch[u].z), dd);
                dd = fdot2f(u2h(cr.w), u2h(ch[u].w), dd);
                float ss = fmaxf(dd + s2[u], 1e-20f);  // (L*dist)^2
                float dist = __builtin_amdgcn_sqrtf(ss);
                float e = __builtin_amdgcn_exp2f(-dist);   // neg = free src modifier
                acc[u] = fmaf(cib.y, e, acc[u]);           // * e^beta_row
            }
            cr = nr; cib = nib;
        }
        float bs = 0.0f;
#pragma unroll
        for (int u = 0; u < JPT; ++u) bs = fmaf(gf[u], acc[u], bs);  // * e^gamma_col
        blocksum = -bs;   // dense term enters LL negatively
    } else {
        // ---------------- sparse link term: Poisson log-likelihood ----------------
        const int base = (blockIdx.x - N_DENSE_BLOCKS) * SPARSE_SPAN + t;
        float val = 0.0f;
        const uint4* hzv = (const uint4*)hz;
#pragma unroll
        for (int u = 0; u < LPT; ++u) {
            const int idx = base + u * 256;
            if (idx >= NNZ_N) continue;
            const int i = spi[idx], j = spj[idx];
            const float c = valueC[idx];
            float dist, bg;
            if (MODE == 0) {
                // fp16 packed path: 16B/row gathers, fp16 biases (L2-resident)
                uint4 ui = hzv[i];
                uint4 uj = hzv[NI_TOT + j];
                float fi[DD], fj[DD];
                unpack_row(ui, fi);
                unpack_row(uj, fj);
                float ss = 0.0f;
#pragma unroll
                for (int d = 0; d < DD; ++d) {
                    float df = fi[d] - fj[d] + EPSF;
                    ss = fmaf(df, df, ss);
                }
                ss = fmaxf(ss, 1e-20f);
                dist = __builtin_amdgcn_sqrtf(ss);
                bg = __half2float(hb[i]) + __half2float(hb[NI_TOT + j]);
            } else {
                // f32 fallback (no workspace)
                const float4* zi4 = (const float4*)(zi_all + (size_t)i * DD);
                const float4* zj4 = (const float4*)(zj_all + (size_t)j * DD);
                float4 a0 = zi4[0], a1 = zi4[1];
                float4 b0 = zj4[0], b1 = zj4[1];
                float ss = 0.0f, df;
                df = a0.x-b0.x+EPSF; ss = fmaf(df,df,ss);
                df = a0.y-b0.y+EPSF; ss = fmaf(df,df,ss);
                df = a0.z-b0.z+EPSF; ss = fmaf(df,df,ss);
                df = a0.w-b0.w+EPSF; ss = fmaf(df,df,ss);
                df = a1.x-b1.x+EPSF; ss = fmaf(df,df,ss);
                df = a1.y-b1.y+EPSF; ss = fmaf(df,df,ss);
                df = a1.z-b1.z+EPSF; ss = fmaf(df,df,ss);
                df = a1.w-b1.w+EPSF; ss = fmaf(df,df,ss);
                ss = fmaxf(ss, 1e-20f);
                dist = __builtin_amdgcn_sqrtf(ss);
                bg = beta[i] + gamma[j];
            }
            // gammaln(c+1) via A&S 6.1.36 poly (|e|<=3e-7), ln = log2/log2e
            float g = 1.0f + c*(GA1 + c*(GA2 + c*(GA3 + c*(GA4 + c*(GA5
                          + c*(GA6 + c*(GA7 + c*GA8)))))));
            val += c * (bg - dist) - __builtin_amdgcn_logf(g) * INV_LOG2E;
        }
        blocksum = val;  // positive sign
    }

    // Block reduction: wave shuffle then cross-wave via LDS
    float acc = blocksum;
#pragma unroll
    for (int off = 32; off; off >>= 1) acc += __shfl_down(acc, off, 64);
    const int lane = t & 63, w = t >> 6;
    if (lane == 0) sRed[w] = acc;
    __syncthreads();
    if (t == 0) {
        float s = sRed[0] + sRed[1] + sRed[2] + sRed[3];
        if (MODE) atomicAdd(out, s);
        else partials[blockIdx.x] = s;
    }
}

__global__ __launch_bounds__(256) void final_reduce_kernel(
    const float* __restrict__ p, int n, float* __restrict__ out)
{
    __shared__ float sRed[4];
    float s0 = 0.0f, s1 = 0.0f, s2 = 0.0f, s3 = 0.0f;
    int i = threadIdx.x;
    for (; i + 768 < n; i += 1024) {      // 4 independent chains to pipeline loads
        s0 += p[i]; s1 += p[i + 256]; s2 += p[i + 512]; s3 += p[i + 768];
    }
    for (; i < n; i += 256) s0 += p[i];
    float s = (s0 + s1) + (s2 + s3);
#pragma unroll
    for (int off = 32; off; off >>= 1) s += __shfl_down(s, off, 64);
    const int lane = threadIdx.x & 63, w = threadIdx.x >> 6;
    if (lane == 0) sRed[w] = s;
    __syncthreads();
    if (threadIdx.x == 0) out[0] = sRed[0] + sRed[1] + sRed[2] + sRed[3];
}

extern "C" void kernel_launch(void* const* d_in, const int* in_sizes, int n_in,
                              void* d_out, int out_size, void* d_ws, size_t ws_size,
                              hipStream_t stream) {
    const float* beta   = (const float*)d_in[0];
    const float* gamma  = (const float*)d_in[1];
    const float* zi     = (const float*)d_in[2];
    const float* zj     = (const float*)d_in[3];
    const float* valueC = (const float*)d_in[4];
    const int* si   = (const int*)d_in[5];
    const int* sjx  = (const int*)d_in[6];
    const int* spi  = (const int*)d_in[7];
    const int* spj  = (const int*)d_in[8];
    float* out = (float*)d_out;

    const int ntot = N_TOTAL_BLOCKS;

    if (d_ws && ws_size >= WS_NEED) {
        __half* hz = (__half*)d_ws;
        __half* hb = (__half*)((char*)d_ws + HZ_BYTES);
        unsigned* irec = (unsigned*)((char*)d_ws + IREC_OFF);
        unsigned* jrec = (unsigned*)((char*)d_ws + JREC_OFF);
        float* p = (float*)((char*)d_ws + PART_OFF);
        const int packb = (2 * NROWS + IREC_N + JREC_N + 255) / 256;  // 1610
        pack_kernel<<<packb, 256, 0, stream>>>(beta, gamma, zi, zj, si, sjx,
                                               hz, hb, irec, jrec);
        fused_kernel<0><<<ntot, 256, 0, stream>>>(
            beta, gamma, zi, zj, valueC, si, sjx, spi, spj,
            hz, hb, irec, jrec, p, out);
        final_reduce_kernel<<<1, 256, 0, stream>>>(p, ntot, out);
    } else {
        // Fallback: f32 sparse + atomic accumulation directly into d_out
        hipMemsetAsync(out, 0, sizeof(float), stream);
        fused_kernel<1><<<ntot, 256, 0, stream>>>(
            beta, gamma, zi, zj, valueC, si, sjx, spi, spj,
            (const __half*)zi, (const __half*)zi, nullptr, nullptr,
            nullptr, out);
    }
}